// Round 9
// baseline (19.152 us; speedup 1.0000x reference)
//
#include <hip/hip_runtime.h>
#include <hip/hip_bf16.h>

#define S_IMG    128
#define KTOP     16
#define RAD2     (0.02f*0.02f)
#define INV_R2   (1.0f/RAD2)
#define RADF     0.02f
#define ZNEARF   1.0f
#define FOCALF   1.7320508075688772f   // 1/tan(30 deg)
#define TPI      16                    // 8x8-pixel tiles, 16 per axis
#define NTILE    (TPI*TPI)             // 256 tiles per image
#define TPB      256                   // 4 waves; 4 sub-lanes per pixel
#define CAP      256                   // worst central 8x8 tile ~150 expected
#define KSENT    0xFFFFFFFFu

__global__ __launch_bounds__(TPB) void render_tile8(
    const float* __restrict__ points,
    const float* __restrict__ eye,
    const float* __restrict__ colors,
    float* __restrict__ out,
    int N)
{
    __shared__ __align__(16) float    s_cx [CAP + 16];
    __shared__ __align__(16) float    s_cy [CAP + 16];
    __shared__ __align__(16) unsigned s_key[CAP + 16];  // (z bits & ~2047) | idx
    __shared__ int s_cnt;

    const int tid = threadIdx.x;
    const int blk = blockIdx.x;
    const int b   = blk >> 8;                  // NTILE == 256
    const int t   = blk & 255;
    const int ty  = t >> 4, tx = t & 15;

    // ---- camera basis (PyTorch3D look_at: at=origin, up=+y; R cols = x,y,z) ----
    const float ex = eye[b*3+0], ey = eye[b*3+1], ez = eye[b*3+2];
    const float zinv = 1.0f / sqrtf(ex*ex + ey*ey + ez*ez);
    const float zax = -ex*zinv, zay = -ey*zinv, zaz = -ez*zinv;
    const float xinv = 1.0f / sqrtf(zaz*zaz + zax*zax);
    const float xax = zaz*xinv, xaz = -zax*xinv;        // x-axis y-component == 0
    const float yax = zay*xaz;
    const float yay = zaz*xax - zax*xaz;
    const float yaz = -zay*xax;

    // ---- tile bbox in NDC (pixel centers) + radius pad ----
    const float cx = 1.0f - (float)(2*(tx*8) + 8) / S_IMG;
    const float cy = 1.0f - (float)(2*(ty*8) + 8) / S_IMG;
    const float hx = 7.0f / S_IMG + RADF + 1e-6f;
    const float hy = 7.0f / S_IMG + RADF + 1e-6f;

    if (tid == 0) s_cnt = 0;
    __syncthreads();

    // ---- phase 1: project + tile-cull; 4 points via 3 coalesced float4 loads ----
    const float4* pq = reinterpret_cast<const float4*>(points + b*N*3);
    const int nquad = N >> 2;                  // 512 quads of 4 points
    for (int qd = tid; qd < nquad; qd += TPB) {
        float4 A = pq[3*qd+0];
        float4 Bv = pq[3*qd+1];
        float4 C = pq[3*qd+2];
        float qx[4] = {A.x, A.w, Bv.z, C.y};
        float qy[4] = {A.y, Bv.x, Bv.w, C.z};
        float qz[4] = {A.z, Bv.y, C.x, C.w};
        #pragma unroll
        for (int u = 0; u < 4; ++u) {          // u static after unroll
            float wx = qx[u] - ex, wy = qy[u] - ey, wz = qz[u] - ez;
            float cz = wx*zax + wy*zay + wz*zaz;
            if (cz > ZNEARF) {
                float inv = FOCALF / cz;
                float xn = (wx*xax + wz*xaz) * inv;
                float yn = (wx*yax + wy*yay + wz*yaz) * inv;
                if (fabsf(xn - cx) <= hx && fabsf(yn - cy) <= hy) {
                    int slot = atomicAdd(&s_cnt, 1);
                    if (slot < CAP) {
                        s_cx [slot] = xn;
                        s_cy [slot] = yn;
                        s_key[slot] = (__float_as_uint(cz) & ~2047u)
                                    | (unsigned)(4*qd + u);
                    }
                }
            }
        }
    }
    __syncthreads();
    int M = s_cnt; if (M > CAP) M = CAP;
    if (tid < 16) {
        s_cx [M + tid] = 1.0e9f;               // never hits
        s_cy [M + tid] = 1.0e9f;
        s_key[M + tid] = KSENT;
    }
    __syncthreads();

    // ---- phase 2: 4 subs/pixel scan segments; per-sub top-16 (key,d2) in regs ----
    const int sub = tid & 3;
    const int p   = tid >> 2;                  // pixel within tile (0..63)
    const int row = ty*8 + (p >> 3);
    const int col = tx*8 + (p & 7);
    const float pxc = 1.0f - (2.0f*col + 1.0f) / S_IMG;
    const float pyc = 1.0f - (2.0f*row + 1.0f) / S_IMG;

    unsigned kb[KTOP];
    float    db[KTOP];
    #pragma unroll
    for (int q = 0; q < KTOP; ++q) { kb[q] = KSENT; db[q] = 0.0f; }

    auto ins = [&](unsigned key, float d2) {
        if (key < kb[KTOP-1]) {
            #pragma unroll
            for (int q = KTOP-1; q >= 1; --q) {
                bool lt  = key < kb[q];
                bool ltp = key < kb[q-1];
                unsigned kq = ltp ? kb[q-1] : key;
                float    dq = ltp ? db[q-1] : d2;
                kb[q] = lt ? kq : kb[q];
                db[q] = lt ? dq : db[q];
            }
            if (key < kb[0]) { kb[0] = key; db[0] = d2; }
        }
    };

    const int L    = 4 * ((M + 15) >> 4);      // per-sub segment, multiple of 4
    const int base = sub * L;                  // max index 4L-1 <= M+15
    const float4* cx4 = reinterpret_cast<const float4*>(s_cx);
    const float4* cy4 = reinterpret_cast<const float4*>(s_cy);
    const uint4*  k4  = reinterpret_cast<const uint4 *>(s_key);

    for (int i = 0; i < L; i += 4) {
        const int qi = (base + i) >> 2;
        float4 vx = cx4[qi];
        float4 vy = cy4[qi];
        uint4  vk = k4 [qi];
        float dx, dy, d2;
        dx = pxc - vx.x; dy = pyc - vy.x; d2 = dx*dx + dy*dy;
        if (d2 < RAD2) ins(vk.x, d2);
        dx = pxc - vx.y; dy = pyc - vy.y; d2 = dx*dx + dy*dy;
        if (d2 < RAD2) ins(vk.y, d2);
        dx = pxc - vx.z; dy = pyc - vy.z; d2 = dx*dx + dy*dy;
        if (d2 < RAD2) ins(vk.z, d2);
        dx = pxc - vx.w; dy = pyc - vy.w; d2 = dx*dx + dy*dy;
        if (d2 < RAD2) ins(vk.w, d2);
    }

    // ---- merge: pop global min across 4 subs, <=16 pops, composite at sub 0 ----
    const float* cols = colors + b*N*3;
    float T = 1.0f, r = 0.0f, g = 0.0f, bl = 0.0f;

    for (int pop = 0; pop < KTOP; ++pop) {
        unsigned mk = kb[0];
        float    md = db[0];
        #pragma unroll
        for (int mx = 1; mx <= 2; mx <<= 1) {  // min over 4-lane group
            unsigned ok = (unsigned)__shfl_xor((int)mk, mx, 64);
            float    od = __shfl_xor(md, mx, 64);
            bool take = ok < mk;
            mk = take ? ok : mk;
            md = take ? od : md;
        }
        if (__all(mk == KSENT)) break;         // all groups exhausted
        if (mk != KSENT && kb[0] == mk) {      // unique owner pops its head
            #pragma unroll
            for (int q = 0; q < KTOP-1; ++q) { kb[q] = kb[q+1]; db[q] = db[q+1]; }
            kb[KTOP-1] = KSENT;
        }
        if (sub == 0 && mk != KSENT) {         // front-to-back composite
            int   j = (int)(mk & 2047u);
            float a = 1.0f - md * INV_R2;
            float w = a * T;
            r  += w * cols[3*j+0];
            g  += w * cols[3*j+1];
            bl += w * cols[3*j+2];
            T  -= T * a;
        }
    }

    if (sub == 0) {
        const int gpix = b * (S_IMG*S_IMG) + row * S_IMG + col;
        float* o = out + (size_t)gpix * 3;
        o[0] = r; o[1] = g; o[2] = bl;
    }
}

extern "C" void kernel_launch(void* const* d_in, const int* in_sizes, int n_in,
                              void* d_out, int out_size, void* d_ws, size_t ws_size,
                              hipStream_t stream)
{
    const float* points = (const float*)d_in[0];
    const float* eye    = (const float*)d_in[1];
    const float* colors = (const float*)d_in[2];
    float* out = (float*)d_out;

    const int B = in_sizes[1] / 3;              // eye is [B,3]
    const int N = in_sizes[0] / (3 * B);        // points is [B,N,3] (N <= 2048)

    render_tile8<<<B * NTILE, TPB, 0, stream>>>(points, eye, colors, out, N);
}

// Round 10
// 14.279 us; speedup vs baseline: 1.3412x; 1.3412x over previous
//
#include <hip/hip_runtime.h>
#include <hip/hip_bf16.h>

#define S_IMG    128
#define KTOP     16
#define RAD2     (0.02f*0.02f)
#define INV_R2   (1.0f/RAD2)
#define RADF     0.02f
#define ZNEARF   1.0f
#define FOCALF   1.7320508075688772f   // 1/tan(30 deg)
#define TPI      16                    // 8x8-pixel tiles, 16 per axis
#define NTILE    (TPI*TPI)             // 256 tiles per image
#define TPB      512                   // 8 waves; 8 sub-lanes per pixel
#define SUBS     8
#define CAP      256                   // worst central 8x8 tile ~100 expected
#define KSENT    0xFFFFFFFFu

__global__ __launch_bounds__(TPB) void render_tile8(
    const float* __restrict__ points,
    const float* __restrict__ eye,
    const float* __restrict__ colors,
    float* __restrict__ out,
    int N)
{
    __shared__ float s_cx[CAP];                          // unsorted candidates
    __shared__ float s_cy[CAP];
    __shared__ __align__(16) unsigned s_key[CAP + 8];    // (z bits & ~2047) | idx
    __shared__ __align__(16) float2   s_sxy [CAP + 32];  // z-sorted (x,y) + sentinels
    __shared__ __align__(16) float4   s_scol[CAP + 32];  // z-sorted (r,g,b,-) + zeros
    __shared__ int s_cnt;

    const int tid  = threadIdx.x;
    const int lane = tid & 63;
    const int blk  = blockIdx.x;
    const int b    = blk >> 8;                 // NTILE == 256
    const int t    = blk & 255;
    const int ty   = t >> 4, tx = t & 15;

    // ---- camera basis (PyTorch3D look_at: at=origin, up=+y; R cols = x,y,z) ----
    const float ex = eye[b*3+0], ey = eye[b*3+1], ez = eye[b*3+2];
    const float zinv = 1.0f / sqrtf(ex*ex + ey*ey + ez*ez);
    const float zax = -ex*zinv, zay = -ey*zinv, zaz = -ez*zinv;
    const float xinv = 1.0f / sqrtf(zaz*zaz + zax*zax);
    const float xax = zaz*xinv, xaz = -zax*xinv;        // x-axis y-component == 0
    const float yax = zay*xaz;
    const float yay = zaz*xax - zax*xaz;
    const float yaz = -zay*xax;

    // ---- tile bbox in NDC (pixel centers) + radius pad ----
    const float cx = 1.0f - (float)(2*(tx*8) + 8) / S_IMG;
    const float cy = 1.0f - (float)(2*(ty*8) + 8) / S_IMG;
    const float hx = 7.0f / S_IMG + RADF + 1e-6f;
    const float hy = 7.0f / S_IMG + RADF + 1e-6f;

    if (tid == 0) s_cnt = 0;
    __syncthreads();

    // ---- phase 1: project + cull; 4 pts via 3 coalesced float4 loads;
    //      wave-aggregated LDS atomic (1 per wave-group instead of per-lane) ----
    const float4* pq = reinterpret_cast<const float4*>(points + b*N*3);
    const int nquad = N >> 2;
    for (int qd = tid; qd < nquad; qd += TPB) {
        float4 A  = pq[3*qd+0];
        float4 Bv = pq[3*qd+1];
        float4 C  = pq[3*qd+2];
        float qx[4] = {A.x, A.w, Bv.z, C.y};
        float qy[4] = {A.y, Bv.x, Bv.w, C.z};
        float qz[4] = {A.z, Bv.y, C.x, C.w};
        #pragma unroll
        for (int u = 0; u < 4; ++u) {
            float wx = qx[u] - ex, wy = qy[u] - ey, wz = qz[u] - ez;
            float cz = wx*zax + wy*zay + wz*zaz;
            float xn = 0.f, yn = 0.f;
            bool keep = (cz > ZNEARF);
            if (keep) {
                float inv = FOCALF / cz;
                xn = (wx*xax + wz*xaz) * inv;
                yn = (wx*yax + wy*yay + wz*yaz) * inv;
                keep = (fabsf(xn - cx) <= hx) && (fabsf(yn - cy) <= hy);
            }
            unsigned long long act = __ballot(keep);
            if (act) {
                int lead = (int)__ffsll(act) - 1;
                int base = 0;
                if (lane == lead) base = atomicAdd(&s_cnt, __popcll(act));
                base = __shfl(base, lead, 64);
                if (keep) {
                    int slot = base + __popcll(act & ((1ull << lane) - 1ull));
                    if (slot < CAP) {
                        s_cx [slot] = xn;
                        s_cy [slot] = yn;
                        s_key[slot] = (__float_as_uint(cz) & ~2047u)
                                    | (unsigned)(4*qd + u);
                    }
                }
            }
        }
    }
    __syncthreads();
    int M = s_cnt; if (M > CAP) M = CAP;

    // ---- sentinel pads ----
    if (tid < 32) {
        if (tid < 8) s_key[M + tid] = KSENT;
        s_sxy [M + tid] = make_float2(1.0e9f, 1.0e9f);   // never hits
        s_scol[M + tid] = make_float4(0.f, 0.f, 0.f, 0.f);
    }
    __syncthreads();

    // ---- phase 2: rank-sort (1 candidate/thread); gather colors ----
    const float* cols = colors + b*N*3;
    if (tid < M) {
        const unsigned mk = s_key[tid];
        const float ux = s_cx[tid], uy = s_cy[tid];
        const uint4* k4 = reinterpret_cast<const uint4*>(s_key);
        const int nb = (M + 7) >> 3;
        int rank = 0;
        for (int q = 0; q < nb; ++q) {                   // broadcast b128 reads
            uint4 a  = k4[2*q];
            uint4 bb = k4[2*q+1];
            rank += (int)(a.x <mk) + (int)(a.y <mk) + (int)(a.z <mk) + (int)(a.w <mk)
                  + (int)(bb.x<mk) + (int)(bb.y<mk) + (int)(bb.z<mk) + (int)(bb.w<mk);
        }
        const int pi = (int)(mk & 2047u);
        s_sxy [rank] = make_float2(ux, uy);
        s_scol[rank] = make_float4(cols[3*pi+0], cols[3*pi+1], cols[3*pi+2], 0.0f);
    }
    __syncthreads();

    // ---- phase 3: 8 subs/pixel scan z-contiguous segments, then merge ----
    const int sub = tid & (SUBS-1);            // subs are adjacent lanes
    const int p   = tid >> 3;                  // pixel within tile (0..63)
    const int row = ty*8 + (p >> 3);
    const int col = tx*8 + (p & 7);
    const float pxc = 1.0f - (2.0f*col + 1.0f) / S_IMG;
    const float pyc = 1.0f - (2.0f*row + 1.0f) / S_IMG;

    const int L    = 4 * ((M + 31) >> 5);      // per-sub segment (multiple of 4)
    const int base = sub * L;                  // max read idx 8L-1 <= M+31

    const float4* xy4 = reinterpret_cast<const float4*>(s_sxy);
    float T = 1.0f, r = 0.0f, g = 0.0f, bl = 0.0f;
    int hits = 0;
    for (int i = 0; i < L; i += 4) {
        const int ii = base + i;
        float4 u   = xy4[(ii >> 1) + 0];
        float4 v   = xy4[(ii >> 1) + 1];
        float4 c0v = s_scol[ii + 0];
        float4 c1v = s_scol[ii + 1];
        float4 c2v = s_scol[ii + 2];
        float4 c3v = s_scol[ii + 3];
        float dx, dy, d2, a, w; bool h;

        dx = pxc - u.x; dy = pyc - u.y; d2 = dx*dx + dy*dy;
        h = (d2 < RAD2); hits += h ? 1 : 0;
        a = h ? 1.0f - d2 * INV_R2 : 0.0f;
        w = a * T; r += w*c0v.x; g += w*c0v.y; bl += w*c0v.z; T -= T*a;

        dx = pxc - u.z; dy = pyc - u.w; d2 = dx*dx + dy*dy;
        h = (d2 < RAD2); hits += h ? 1 : 0;
        a = h ? 1.0f - d2 * INV_R2 : 0.0f;
        w = a * T; r += w*c1v.x; g += w*c1v.y; bl += w*c1v.z; T -= T*a;

        dx = pxc - v.x; dy = pyc - v.y; d2 = dx*dx + dy*dy;
        h = (d2 < RAD2); hits += h ? 1 : 0;
        a = h ? 1.0f - d2 * INV_R2 : 0.0f;
        w = a * T; r += w*c2v.x; g += w*c2v.y; bl += w*c2v.z; T -= T*a;

        dx = pxc - v.z; dy = pyc - v.w; d2 = dx*dx + dy*dy;
        h = (d2 < RAD2); hits += h ? 1 : 0;
        a = h ? 1.0f - d2 * INV_R2 : 0.0f;
        w = a * T; r += w*c3v.x; g += w*c3v.y; bl += w*c3v.z; T -= T*a;
    }

    // ordered over-compose across the 8 subs (associative, non-commutative)
    #pragma unroll
    for (int mx = 1; mx <= 4; mx <<= 1) {
        float pr = __shfl_xor(r,  mx, 64);
        float pg = __shfl_xor(g,  mx, 64);
        float pb = __shfl_xor(bl, mx, 64);
        float pT = __shfl_xor(T,  mx, 64);
        int   ph = __shfl_xor(hits, mx, 64);
        const bool lower = (sub & mx) == 0;    // my segment precedes partner's
        r  = lower ? r  + T*pr : pr + pT*r;
        g  = lower ? g  + T*pg : pg + pT*g;
        bl = lower ? bl + T*pb : pb + pT*bl;
        T  = lower ? T*pT      : pT*T;
        hits += ph;
    }

    if (sub == 0) {
        if (hits > KTOP) {                     // exact K-cap fallback (≈ never)
            T = 1.0f; r = 0.0f; g = 0.0f; bl = 0.0f;
            int hh = 0;
            for (int i = 0; i < M && hh < KTOP; ++i) {
                float2 xy = s_sxy[i];
                float dx = pxc - xy.x, dy = pyc - xy.y;
                float d2 = dx*dx + dy*dy;
                if (d2 < RAD2) {
                    float4 cc = s_scol[i];
                    float a = 1.0f - d2 * INV_R2;
                    float w = a * T;
                    r += w*cc.x; g += w*cc.y; bl += w*cc.z;
                    T -= T*a; ++hh;
                }
            }
        }
        const int gpix = b * (S_IMG*S_IMG) + row * S_IMG + col;
        float* o = out + (size_t)gpix * 3;
        o[0] = r; o[1] = g; o[2] = bl;
    }
}

extern "C" void kernel_launch(void* const* d_in, const int* in_sizes, int n_in,
                              void* d_out, int out_size, void* d_ws, size_t ws_size,
                              hipStream_t stream)
{
    const float* points = (const float*)d_in[0];
    const float* eye    = (const float*)d_in[1];
    const float* colors = (const float*)d_in[2];
    float* out = (float*)d_out;

    const int B = in_sizes[1] / 3;              // eye is [B,3]
    const int N = in_sizes[0] / (3 * B);        // points is [B,N,3] (N <= 2048)

    render_tile8<<<B * NTILE, TPB, 0, stream>>>(points, eye, colors, out, N);
}